// Round 7
// baseline (381.960 us; speedup 1.0000x reference)
//
#include <hip/hip_runtime.h>
#include <hip/hip_bf16.h>

typedef __bf16 bf16_t;
typedef __attribute__((ext_vector_type(8))) __bf16 bf16x8;
typedef __attribute__((ext_vector_type(4))) float f32x4;

#define EPSF 1e-5f

// ===========================================================================
// K1. Grid 768 x 256 (3 blocks/CU)  [r5 champion config]:
//   blocks [0,128):   gemm_ai dual-nt + folded ej GEMV + attn-logit -> ws_lp
//   blocks [128,256): gemm_fh dual-nt -> ws_fh
//   blocks [256,768): input-gemvs, 16 rows/block, 4 rows/wave, pairwise
//                     batched loads: rows [0,2048)=W_fi -> ws_fi,
//                     rows [2048,8192)=W_iou[:, :2048] -> ws_iou partial
// ===========================================================================
__global__ __launch_bounds__(256, 3) void k1_streams(
    const float* __restrict__ hiddens, const float* __restrict__ external,
    const float* __restrict__ input,
    const float* __restrict__ W_ai, const float* __restrict__ W_fh,
    const float* __restrict__ W_fi, const float* __restrict__ W_iou,
    const float* __restrict__ W_attn,
    float* __restrict__ lp, float* __restrict__ fh_out,
    float* __restrict__ fi_out, float* __restrict__ iou_out)
{
    __shared__ float red[4][2][16][16];
    __shared__ float ejs[4][16];

    int b    = blockIdx.x;
    int tid  = threadIdx.x;
    int wave = tid >> 6;
    int lane = tid & 63;

    if (b < 256) {
        bool is_ai = (b < 128);
        int  jt    = is_ai ? b : b - 128;
        int  l15   = lane & 15;
        int  quad  = lane >> 4;
        int  k0    = wave * 512;
        int  wstride = is_ai ? 4096 : 2048;
        const float* W = is_ai ? W_ai : W_fh;

        const float* a0p = hiddens + (size_t)l15 * 2048 + quad * 8 + k0;
        const float* a1p = hiddens + (size_t)(16 + l15) * 2048 + quad * 8 + k0;
        const float* bp  = W + (size_t)(jt * 16 + l15) * wstride + quad * 8 + k0;

        f32x4 acc0 = {0.f, 0.f, 0.f, 0.f};
        f32x4 acc1 = {0.f, 0.f, 0.f, 0.f};
        float ejacc = 0.f;

        if (is_ai) {
            const float* ep = bp + 2048;
            const float* xp = external + quad * 8 + k0;
            #pragma unroll 2
            for (int k = 0; k < 512; k += 32) {
                float4 p0 = *(const float4*)(a0p + k);
                float4 p1 = *(const float4*)(a0p + k + 4);
                float4 q0 = *(const float4*)(a1p + k);
                float4 q1 = *(const float4*)(a1p + k + 4);
                float4 b0 = *(const float4*)(bp + k);
                float4 b1 = *(const float4*)(bp + k + 4);
                float4 e0 = *(const float4*)(ep + k);
                float4 e1 = *(const float4*)(ep + k + 4);
                float4 x0 = *(const float4*)(xp + k);
                float4 x1 = *(const float4*)(xp + k + 4);
                bf16x8 av0, av1, bv;
                av0[0]=(bf16_t)p0.x; av0[1]=(bf16_t)p0.y; av0[2]=(bf16_t)p0.z; av0[3]=(bf16_t)p0.w;
                av0[4]=(bf16_t)p1.x; av0[5]=(bf16_t)p1.y; av0[6]=(bf16_t)p1.z; av0[7]=(bf16_t)p1.w;
                av1[0]=(bf16_t)q0.x; av1[1]=(bf16_t)q0.y; av1[2]=(bf16_t)q0.z; av1[3]=(bf16_t)q0.w;
                av1[4]=(bf16_t)q1.x; av1[5]=(bf16_t)q1.y; av1[6]=(bf16_t)q1.z; av1[7]=(bf16_t)q1.w;
                bv[0]=(bf16_t)b0.x; bv[1]=(bf16_t)b0.y; bv[2]=(bf16_t)b0.z; bv[3]=(bf16_t)b0.w;
                bv[4]=(bf16_t)b1.x; bv[5]=(bf16_t)b1.y; bv[6]=(bf16_t)b1.z; bv[7]=(bf16_t)b1.w;
                acc0 = __builtin_amdgcn_mfma_f32_16x16x32_bf16(av0, bv, acc0, 0, 0, 0);
                acc1 = __builtin_amdgcn_mfma_f32_16x16x32_bf16(av1, bv, acc1, 0, 0, 0);
                ejacc += e0.x*x0.x + e0.y*x0.y + e0.z*x0.z + e0.w*x0.w
                       + e1.x*x1.x + e1.y*x1.y + e1.z*x1.z + e1.w*x1.w;
            }
            ejacc += __shfl_xor(ejacc, 16, 64);
            ejacc += __shfl_xor(ejacc, 32, 64);
            if (quad == 0) ejs[wave][l15] = ejacc;
        } else {
            #pragma unroll 2
            for (int k = 0; k < 512; k += 32) {
                float4 p0 = *(const float4*)(a0p + k);
                float4 p1 = *(const float4*)(a0p + k + 4);
                float4 q0 = *(const float4*)(a1p + k);
                float4 q1 = *(const float4*)(a1p + k + 4);
                float4 b0 = *(const float4*)(bp + k);
                float4 b1 = *(const float4*)(bp + k + 4);
                bf16x8 av0, av1, bv;
                av0[0]=(bf16_t)p0.x; av0[1]=(bf16_t)p0.y; av0[2]=(bf16_t)p0.z; av0[3]=(bf16_t)p0.w;
                av0[4]=(bf16_t)p1.x; av0[5]=(bf16_t)p1.y; av0[6]=(bf16_t)p1.z; av0[7]=(bf16_t)p1.w;
                av1[0]=(bf16_t)q0.x; av1[1]=(bf16_t)q0.y; av1[2]=(bf16_t)q0.z; av1[3]=(bf16_t)q0.w;
                av1[4]=(bf16_t)q1.x; av1[5]=(bf16_t)q1.y; av1[6]=(bf16_t)q1.z; av1[7]=(bf16_t)q1.w;
                bv[0]=(bf16_t)b0.x; bv[1]=(bf16_t)b0.y; bv[2]=(bf16_t)b0.z; bv[3]=(bf16_t)b0.w;
                bv[4]=(bf16_t)b1.x; bv[5]=(bf16_t)b1.y; bv[6]=(bf16_t)b1.z; bv[7]=(bf16_t)b1.w;
                acc0 = __builtin_amdgcn_mfma_f32_16x16x32_bf16(av0, bv, acc0, 0, 0, 0);
                acc1 = __builtin_amdgcn_mfma_f32_16x16x32_bf16(av1, bv, acc1, 0, 0, 0);
            }
        }

        #pragma unroll
        for (int r = 0; r < 4; ++r) {
            red[wave][0][quad * 4 + r][l15] = acc0[r];
            red[wave][1][quad * 4 + r][l15] = acc1[r];
        }
        __syncthreads();

        int row = tid >> 4, col = tid & 15;
        #pragma unroll
        for (int nt = 0; nt < 2; ++nt) {
            float s = red[0][nt][row][col] + red[1][nt][row][col]
                    + red[2][nt][row][col] + red[3][nt][row][col];
            if (is_ai) {
                float ej = ejs[0][col] + ejs[1][col] + ejs[2][col] + ejs[3][col];
                float lg = tanhf(s + ej) * W_attn[jt * 16 + col];
                lg += __shfl_xor(lg, 1, 64);
                lg += __shfl_xor(lg, 2, 64);
                lg += __shfl_xor(lg, 4, 64);
                lg += __shfl_xor(lg, 8, 64);
                if (col == 0) lp[jt * 32 + nt * 16 + row] = lg;
            } else {
                fh_out[(size_t)(nt * 16 + row) * 2048 + jt * 16 + col] = s;
            }
        }
    } else {
        const float4* in4 = (const float4*)input;
        float4 xr[8];
        #pragma unroll
        for (int k = 0; k < 8; ++k) xr[k] = in4[lane + 64 * k];

        int r0 = (b - 256) * 16 + wave * 4;
        #pragma unroll
        for (int p = 0; p < 2; ++p) {
            int ra = r0 + p * 2;
            int rb = ra + 1;
            const float4* wa = (ra < 2048)
                ? (const float4*)(W_fi + (size_t)ra * 2048)
                : (const float4*)(W_iou + (size_t)(ra - 2048) * 4096);
            const float4* wb = (rb < 2048)
                ? (const float4*)(W_fi + (size_t)rb * 2048)
                : (const float4*)(W_iou + (size_t)(rb - 2048) * 4096);
            float4 A[8], B[8];
            #pragma unroll
            for (int k = 0; k < 8; ++k) { A[k] = wa[lane + 64 * k]; B[k] = wb[lane + 64 * k]; }
            float accA = 0.f, accB = 0.f;
            #pragma unroll
            for (int k = 0; k < 8; ++k) {
                accA += A[k].x*xr[k].x + A[k].y*xr[k].y + A[k].z*xr[k].z + A[k].w*xr[k].w;
                accB += B[k].x*xr[k].x + B[k].y*xr[k].y + B[k].z*xr[k].z + B[k].w*xr[k].w;
            }
            #pragma unroll
            for (int off = 32; off; off >>= 1) {
                accA += __shfl_down(accA, off, 64);
                accB += __shfl_down(accB, off, 64);
            }
            if (lane == 0) {
                if (ra < 2048) fi_out[ra] = accA; else iou_out[ra - 2048] = accA;
                if (rb < 2048) fi_out[rb] = accB; else iou_out[rb - 2048] = accB;
            }
        }
    }
}

// ===========================================================================
// K2. Grid 40 x 256:
//   blocks [0,32):  per-child LN stats of f_lin[n] = fi + fh[n] -> frs[n]
//   blocks [32,40): reduce lp partials -> softmax over 32 -> merged slice
// ===========================================================================
__global__ __launch_bounds__(256) void k2_mid(
    const float* __restrict__ fi, const float* __restrict__ fh,
    const float* __restrict__ lp, const float* __restrict__ hiddens,
    float* __restrict__ frs, float* __restrict__ merged)
{
    __shared__ float s1[256], s2[256];
    int b = blockIdx.x, t = threadIdx.x;

    if (b < 32) {
        int n = b;
        float sum = 0.f, sq = 0.f;
        #pragma unroll
        for (int i = 0; i < 8; ++i) {
            int h = t * 8 + i;
            float v = fi[h] + fh[n * 2048 + h];
            sum += v; sq += v * v;
        }
        s1[t] = sum; s2[t] = sq;
        __syncthreads();
        for (int off = 128; off; off >>= 1) {
            if (t < off) { s1[t] += s1[t + off]; s2[t] += s2[t + off]; }
            __syncthreads();
        }
        if (t == 0) {
            const float inv = 1.f / 2048.f;
            float mean = s1[0] * inv;
            frs[n * 2]     = mean;
            frs[n * 2 + 1] = rsqrtf(s2[0] * inv - mean * mean + EPSF);
        }
    } else {
        __shared__ float lred[32][8];
        __shared__ float attnw[32];
        int n = t >> 3, sl = t & 7;
        float p = 0.f;
        #pragma unroll
        for (int m = 0; m < 16; ++m) p += lp[(sl * 16 + m) * 32 + n];
        lred[n][sl] = p;
        __syncthreads();
        if (sl == 0) {
            float lg = 0.f;
            #pragma unroll
            for (int m = 0; m < 8; ++m) lg += lred[n][m];
            lred[n][0] = lg;
        }
        __syncthreads();
        if (t < 32) {
            float mx = -1e30f;
            for (int m = 0; m < 32; ++m) mx = fmaxf(mx, lred[m][0]);
            float ssum = 0.f;
            for (int m = 0; m < 32; ++m) ssum += expf(lred[m][0] - mx);
            attnw[t] = expf(lred[t][0] - mx) / ssum;
        }
        __syncthreads();
        int h = (b - 32) * 256 + t;
        float acc = 0.f;
        #pragma unroll 8
        for (int n2 = 0; n2 < 32; ++n2) acc += attnw[n2] * hiddens[n2 * 2048 + h];
        merged[h] = acc;
    }
}

// ===========================================================================
// K3. Grid 264 x 256:
//   blocks [0,256):   mm = W_merge @ merged, 8 rows/block, 2 rows/wave,
//                     pairwise batched loads.
//   blocks [256,264): fc[h] = sum_n sigmoid(LN_n(fi+fh)[h]*g+b)*cells[n][h]
//   block 263 thread 0 additionally zeroes the K4 last-block counter
//   (K3 completes before K4 starts on the stream -> visible, no memset).
// ===========================================================================
__global__ __launch_bounds__(256) void k3_mid(
    const float* __restrict__ W_merge, const float* __restrict__ merged,
    const float* __restrict__ fi, const float* __restrict__ fh,
    const float* __restrict__ frs, const float* __restrict__ gf,
    const float* __restrict__ bf_, const float* __restrict__ cells,
    float* __restrict__ mm, float* __restrict__ fc,
    int* __restrict__ done)
{
    int b = blockIdx.x, t = threadIdx.x;
    int wave = t >> 6, lane = t & 63;
    if (b < 256) {
        const float4* xp = (const float4*)merged;
        float4 xr[8];
        #pragma unroll
        for (int k = 0; k < 8; ++k) xr[k] = xp[lane + 64 * k];

        int ra = b * 8 + wave * 2;
        int rb = ra + 1;
        const float4* wa = (const float4*)(W_merge + (size_t)ra * 2048);
        const float4* wb = (const float4*)(W_merge + (size_t)rb * 2048);
        float4 A[8], B[8];
        #pragma unroll
        for (int k = 0; k < 8; ++k) { A[k] = wa[lane + 64 * k]; B[k] = wb[lane + 64 * k]; }
        float accA = 0.f, accB = 0.f;
        #pragma unroll
        for (int k = 0; k < 8; ++k) {
            accA += A[k].x*xr[k].x + A[k].y*xr[k].y + A[k].z*xr[k].z + A[k].w*xr[k].w;
            accB += B[k].x*xr[k].x + B[k].y*xr[k].y + B[k].z*xr[k].z + B[k].w*xr[k].w;
        }
        #pragma unroll
        for (int off = 32; off; off >>= 1) {
            accA += __shfl_down(accA, off, 64);
            accB += __shfl_down(accB, off, 64);
        }
        if (lane == 0) { mm[ra] = accA; mm[rb] = accB; }
    } else {
        if (b == 263 && t == 0) *done = 0;
        int h = (b - 256) * 256 + t;
        float g = gf[h], bb = bf_[h], f_i = fi[h];
        float acc = 0.f;
        #pragma unroll 8
        for (int n = 0; n < 32; ++n) {
            float v = (f_i + fh[n * 2048 + h] - frs[n * 2]) * frs[n * 2 + 1] * g + bb;
            float f = 1.f / (1.f + expf(-v));
            acc += f * cells[n * 2048 + h];
        }
        fc[h] = acc;
    }
}

// ===========================================================================
// K4. Grid 768 x 256 (3 blocks/CU): iou mh-half + fused tail.
// Block prologue: mh = tanh(LN(mm)*g+b) once into LDS (shfl + LDS combine).
// Then 2 rows/wave of W_iou[:, 2048:], all 16 row-loads batched before any
// reduce; iou[row] += dot (input-half partial from K1).
// LAST block to finish (atomic counter, no spinning) runs the tail -> out.
// ===========================================================================
__global__ __launch_bounds__(256, 3) void k4_mh_tail(
    const float* __restrict__ W_iou, const float* __restrict__ mm,
    const float* __restrict__ g_merge, const float* __restrict__ b_merge,
    float* __restrict__ iou, const float* __restrict__ fc,
    const float* __restrict__ gi, const float* __restrict__ bi,
    const float* __restrict__ go, const float* __restrict__ bo,
    const float* __restrict__ gu, const float* __restrict__ bu,
    const float* __restrict__ gc, const float* __restrict__ bc,
    int* __restrict__ done, float* __restrict__ out)
{
    __shared__ float mh_lds[2048];
    __shared__ float pr[4][2];
    __shared__ int   is_last;
    int b = blockIdx.x, t = threadIdx.x;
    int wave = t >> 6, lane = t & 63;

    const float4* mm4 = (const float4*)mm;
    const float4* g4  = (const float4*)g_merge;
    const float4* b4  = (const float4*)b_merge;

    float4 m0 = mm4[t * 2], m1 = mm4[t * 2 + 1];
    float sum = m0.x + m0.y + m0.z + m0.w + m1.x + m1.y + m1.z + m1.w;
    float sq  = m0.x*m0.x + m0.y*m0.y + m0.z*m0.z + m0.w*m0.w
              + m1.x*m1.x + m1.y*m1.y + m1.z*m1.z + m1.w*m1.w;
    #pragma unroll
    for (int off = 1; off < 64; off <<= 1) {
        sum += __shfl_xor(sum, off, 64);
        sq  += __shfl_xor(sq,  off, 64);
    }
    if (lane == 0) { pr[wave][0] = sum; pr[wave][1] = sq; }
    __syncthreads();
    sum = pr[0][0] + pr[1][0] + pr[2][0] + pr[3][0];
    sq  = pr[0][1] + pr[1][1] + pr[2][1] + pr[3][1];
    const float inv = 1.f / 2048.f;
    float mean = sum * inv;
    float r = rsqrtf(sq * inv - mean * mean + EPSF);

    float4 g0 = g4[t * 2], g1 = g4[t * 2 + 1];
    float4 c0 = b4[t * 2], c1 = b4[t * 2 + 1];
    float4 h0, h1;
    h0.x = tanhf((m0.x - mean) * r * g0.x + c0.x);
    h0.y = tanhf((m0.y - mean) * r * g0.y + c0.y);
    h0.z = tanhf((m0.z - mean) * r * g0.z + c0.z);
    h0.w = tanhf((m0.w - mean) * r * g0.w + c0.w);
    h1.x = tanhf((m1.x - mean) * r * g1.x + c1.x);
    h1.y = tanhf((m1.y - mean) * r * g1.y + c1.y);
    h1.z = tanhf((m1.z - mean) * r * g1.z + c1.z);
    h1.w = tanhf((m1.w - mean) * r * g1.w + c1.w);
    ((float4*)mh_lds)[t * 2]     = h0;
    ((float4*)mh_lds)[t * 2 + 1] = h1;
    __syncthreads();

    float4 xr[8];
    #pragma unroll
    for (int k = 0; k < 8; ++k) xr[k] = ((const float4*)mh_lds)[lane + 64 * k];

    int ra = b * 8 + wave * 2;
    int rb = ra + 1;
    const float4* wa = (const float4*)(W_iou + (size_t)ra * 4096 + 2048);
    const float4* wb = (const float4*)(W_iou + (size_t)rb * 4096 + 2048);
    float4 A[8], B[8];
    #pragma unroll
    for (int k = 0; k < 8; ++k) { A[k] = wa[lane + 64 * k]; B[k] = wb[lane + 64 * k]; }
    float accA = 0.f, accB = 0.f;
    #pragma unroll
    for (int k = 0; k < 8; ++k) {
        accA += A[k].x*xr[k].x + A[k].y*xr[k].y + A[k].z*xr[k].z + A[k].w*xr[k].w;
        accB += B[k].x*xr[k].x + B[k].y*xr[k].y + B[k].z*xr[k].z + B[k].w*xr[k].w;
    }
    #pragma unroll
    for (int off = 32; off; off >>= 1) {
        accA += __shfl_down(accA, off, 64);
        accB += __shfl_down(accB, off, 64);
    }
    if (lane == 0) { iou[ra] += accA; iou[rb] += accB; }

    // -------- last-block-done gate (no spinning, deadlock-free) --------
    __threadfence();
    __syncthreads();
    if (t == 0) {
        int old = __hip_atomic_fetch_add(done, 1, __ATOMIC_ACQ_REL, __HIP_MEMORY_SCOPE_AGENT);
        is_last = (old == (int)gridDim.x - 1);
    }
    __syncthreads();
    if (!is_last) return;
    __threadfence();

    // -------- fused tail (one block): i/o/u LN + gates + cell LN -> out ----
    {
        __shared__ float sA[6][256];
        float vi[8], vo[8], vu[8];
        float si = 0, qi = 0, so = 0, qo = 0, su = 0, qu = 0;
        #pragma unroll
        for (int i = 0; i < 8; ++i) {
            int h = t * 8 + i;
            vi[i] = iou[h]; vo[i] = iou[2048 + h]; vu[i] = iou[4096 + h];
            si += vi[i]; qi += vi[i] * vi[i];
            so += vo[i]; qo += vo[i] * vo[i];
            su += vu[i]; qu += vu[i] * vu[i];
        }
        sA[0][t] = si; sA[1][t] = qi; sA[2][t] = so;
        sA[3][t] = qo; sA[4][t] = su; sA[5][t] = qu;
        __syncthreads();
        for (int off = 128; off; off >>= 1) {
            if (t < off) {
                #pragma unroll
                for (int c = 0; c < 6; ++c) sA[c][t] += sA[c][t + off];
            }
            __syncthreads();
        }
        float mi = sA[0][0] * inv, ri = rsqrtf(sA[1][0] * inv - mi * mi + EPSF);
        float mo = sA[2][0] * inv, ro = rsqrtf(sA[3][0] * inv - mo * mo + EPSF);
        float mu = sA[4][0] * inv, ru = rsqrtf(sA[5][0] * inv - mu * mu + EPSF);
        __syncthreads();

        float o_[8], v_[8];
        float sv = 0, qv = 0;
        #pragma unroll
        for (int i = 0; i < 8; ++i) {
            int h = t * 8 + i;
            float ivl = 1.f / (1.f + expf(-((vi[i] - mi) * ri * gi[h] + bi[h])));
            o_[i]     = 1.f / (1.f + expf(-((vo[i] - mo) * ro * go[h] + bo[h])));
            float uvl = tanhf((vu[i] - mu) * ru * gu[h] + bu[h]);
            v_[i] = ivl * uvl + fc[h];
            sv += v_[i]; qv += v_[i] * v_[i];
        }
        sA[0][t] = sv; sA[1][t] = qv;
        __syncthreads();
        for (int off = 128; off; off >>= 1) {
            if (t < off) { sA[0][t] += sA[0][t + off]; sA[1][t] += sA[1][t + off]; }
            __syncthreads();
        }
        float mc = sA[0][0] * inv, rc = rsqrtf(sA[1][0] * inv - mc * mc + EPSF);
        #pragma unroll
        for (int i = 0; i < 8; ++i) {
            int h = t * 8 + i;
            float nc = (v_[i] - mc) * rc * gc[h] + bc[h];
            float nh = o_[i] * tanhf(nc);
            out[h]        = nh;
            out[2048 + h] = nc;
        }
    }
}

// ---------------------------------------------------------------------------
extern "C" void kernel_launch(void* const* d_in, const int* in_sizes, int n_in,
                              void* d_out, int out_size, void* d_ws, size_t ws_size,
                              hipStream_t stream)
{
    const float* input    = (const float*)d_in[0];
    const float* hiddens  = (const float*)d_in[1];
    const float* cells    = (const float*)d_in[2];
    const float* external = (const float*)d_in[3];
    const float* W_ai     = (const float*)d_in[4];
    const float* W_attn   = (const float*)d_in[5];
    const float* W_merge  = (const float*)d_in[6];
    const float* W_iou    = (const float*)d_in[7];
    const float* W_fi     = (const float*)d_in[8];
    const float* W_fh     = (const float*)d_in[9];
    const float* g_merge  = (const float*)d_in[10];
    const float* b_merge  = (const float*)d_in[11];
    const float* g_f      = (const float*)d_in[12];
    const float* b_f      = (const float*)d_in[13];
    const float* g_i      = (const float*)d_in[14];
    const float* b_i      = (const float*)d_in[15];
    const float* g_o      = (const float*)d_in[16];
    const float* b_o      = (const float*)d_in[17];
    const float* g_u      = (const float*)d_in[18];
    const float* b_u      = (const float*)d_in[19];
    const float* g_c      = (const float*)d_in[20];
    const float* b_c      = (const float*)d_in[21];

    float* ws = (float*)d_ws;
    float* ws_fh     = ws;              // 32*2048 = 65536
    float* ws_fi     = ws + 65536;      // 2048
    float* ws_lp     = ws + 67584;      // 128*32 = 4096
    float* ws_frs    = ws + 71680;      // 64
    float* ws_merged = ws + 71744;      // 2048
    float* ws_mm     = ws + 73792;      // 2048
    float* ws_fc     = ws + 75840;      // 2048
    float* ws_iou    = ws + 77888;      // 6144
    int*   ws_done   = (int*)(ws + 84032);
    float* out = (float*)d_out;

    k1_streams<<<768, 256, 0, stream>>>(hiddens, external, input,
                                        W_ai, W_fh, W_fi, W_iou, W_attn,
                                        ws_lp, ws_fh, ws_fi, ws_iou);
    k2_mid<<<40, 256, 0, stream>>>(ws_fi, ws_fh, ws_lp, hiddens,
                                   ws_frs, ws_merged);
    k3_mid<<<264, 256, 0, stream>>>(W_merge, ws_merged, ws_fi, ws_fh,
                                    ws_frs, g_f, b_f, cells, ws_mm, ws_fc,
                                    ws_done);
    k4_mh_tail<<<768, 256, 0, stream>>>(W_iou, ws_mm, g_merge, b_merge,
                                        ws_iou, ws_fc, g_i, b_i, g_o, b_o,
                                        g_u, b_u, g_c, b_c, ws_done, out);
}

// Round 8
// 276.399 us; speedup vs baseline: 1.3819x; 1.3819x over previous
//
#include <hip/hip_runtime.h>
#include <hip/hip_bf16.h>

typedef __bf16 bf16_t;
typedef __attribute__((ext_vector_type(8))) __bf16 bf16x8;
typedef __attribute__((ext_vector_type(4))) float f32x4;

#define EPSF 1e-5f

// ===========================================================================
// K1. Grid 768 x 256 (3 blocks/CU)  [r5 champion config]:
//   blocks [0,128):   gemm_ai dual-nt + folded ej GEMV + attn-logit -> ws_lp
//   blocks [128,256): gemm_fh dual-nt -> ws_fh
//   blocks [256,768): input-gemvs, 16 rows/block, 4 rows/wave, pairwise
//                     batched loads: rows [0,2048)=W_fi -> ws_fi,
//                     rows [2048,8192)=W_iou[:, :2048] -> ws_iou partial
// NOTE: no device-scope fences/atomics anywhere (r7 lesson: a per-block
// __threadfence on a wide grid costs ~100us in L2 writebacks on MI355X).
// ===========================================================================
__global__ __launch_bounds__(256, 3) void k1_streams(
    const float* __restrict__ hiddens, const float* __restrict__ external,
    const float* __restrict__ input,
    const float* __restrict__ W_ai, const float* __restrict__ W_fh,
    const float* __restrict__ W_fi, const float* __restrict__ W_iou,
    const float* __restrict__ W_attn,
    float* __restrict__ lp, float* __restrict__ fh_out,
    float* __restrict__ fi_out, float* __restrict__ iou_out)
{
    __shared__ float red[4][2][16][16];
    __shared__ float ejs[4][16];

    int b    = blockIdx.x;
    int tid  = threadIdx.x;
    int wave = tid >> 6;
    int lane = tid & 63;

    if (b < 256) {
        bool is_ai = (b < 128);
        int  jt    = is_ai ? b : b - 128;
        int  l15   = lane & 15;
        int  quad  = lane >> 4;
        int  k0    = wave * 512;
        int  wstride = is_ai ? 4096 : 2048;
        const float* W = is_ai ? W_ai : W_fh;

        const float* a0p = hiddens + (size_t)l15 * 2048 + quad * 8 + k0;
        const float* a1p = hiddens + (size_t)(16 + l15) * 2048 + quad * 8 + k0;
        const float* bp  = W + (size_t)(jt * 16 + l15) * wstride + quad * 8 + k0;

        f32x4 acc0 = {0.f, 0.f, 0.f, 0.f};
        f32x4 acc1 = {0.f, 0.f, 0.f, 0.f};
        float ejacc = 0.f;

        if (is_ai) {
            const float* ep = bp + 2048;
            const float* xp = external + quad * 8 + k0;
            #pragma unroll 2
            for (int k = 0; k < 512; k += 32) {
                float4 p0 = *(const float4*)(a0p + k);
                float4 p1 = *(const float4*)(a0p + k + 4);
                float4 q0 = *(const float4*)(a1p + k);
                float4 q1 = *(const float4*)(a1p + k + 4);
                float4 b0 = *(const float4*)(bp + k);
                float4 b1 = *(const float4*)(bp + k + 4);
                float4 e0 = *(const float4*)(ep + k);
                float4 e1 = *(const float4*)(ep + k + 4);
                float4 x0 = *(const float4*)(xp + k);
                float4 x1 = *(const float4*)(xp + k + 4);
                bf16x8 av0, av1, bv;
                av0[0]=(bf16_t)p0.x; av0[1]=(bf16_t)p0.y; av0[2]=(bf16_t)p0.z; av0[3]=(bf16_t)p0.w;
                av0[4]=(bf16_t)p1.x; av0[5]=(bf16_t)p1.y; av0[6]=(bf16_t)p1.z; av0[7]=(bf16_t)p1.w;
                av1[0]=(bf16_t)q0.x; av1[1]=(bf16_t)q0.y; av1[2]=(bf16_t)q0.z; av1[3]=(bf16_t)q0.w;
                av1[4]=(bf16_t)q1.x; av1[5]=(bf16_t)q1.y; av1[6]=(bf16_t)q1.z; av1[7]=(bf16_t)q1.w;
                bv[0]=(bf16_t)b0.x; bv[1]=(bf16_t)b0.y; bv[2]=(bf16_t)b0.z; bv[3]=(bf16_t)b0.w;
                bv[4]=(bf16_t)b1.x; bv[5]=(bf16_t)b1.y; bv[6]=(bf16_t)b1.z; bv[7]=(bf16_t)b1.w;
                acc0 = __builtin_amdgcn_mfma_f32_16x16x32_bf16(av0, bv, acc0, 0, 0, 0);
                acc1 = __builtin_amdgcn_mfma_f32_16x16x32_bf16(av1, bv, acc1, 0, 0, 0);
                ejacc += e0.x*x0.x + e0.y*x0.y + e0.z*x0.z + e0.w*x0.w
                       + e1.x*x1.x + e1.y*x1.y + e1.z*x1.z + e1.w*x1.w;
            }
            ejacc += __shfl_xor(ejacc, 16, 64);
            ejacc += __shfl_xor(ejacc, 32, 64);
            if (quad == 0) ejs[wave][l15] = ejacc;
        } else {
            #pragma unroll 2
            for (int k = 0; k < 512; k += 32) {
                float4 p0 = *(const float4*)(a0p + k);
                float4 p1 = *(const float4*)(a0p + k + 4);
                float4 q0 = *(const float4*)(a1p + k);
                float4 q1 = *(const float4*)(a1p + k + 4);
                float4 b0 = *(const float4*)(bp + k);
                float4 b1 = *(const float4*)(bp + k + 4);
                bf16x8 av0, av1, bv;
                av0[0]=(bf16_t)p0.x; av0[1]=(bf16_t)p0.y; av0[2]=(bf16_t)p0.z; av0[3]=(bf16_t)p0.w;
                av0[4]=(bf16_t)p1.x; av0[5]=(bf16_t)p1.y; av0[6]=(bf16_t)p1.z; av0[7]=(bf16_t)p1.w;
                av1[0]=(bf16_t)q0.x; av1[1]=(bf16_t)q0.y; av1[2]=(bf16_t)q0.z; av1[3]=(bf16_t)q0.w;
                av1[4]=(bf16_t)q1.x; av1[5]=(bf16_t)q1.y; av1[6]=(bf16_t)q1.z; av1[7]=(bf16_t)q1.w;
                bv[0]=(bf16_t)b0.x; bv[1]=(bf16_t)b0.y; bv[2]=(bf16_t)b0.z; bv[3]=(bf16_t)b0.w;
                bv[4]=(bf16_t)b1.x; bv[5]=(bf16_t)b1.y; bv[6]=(bf16_t)b1.z; bv[7]=(bf16_t)b1.w;
                acc0 = __builtin_amdgcn_mfma_f32_16x16x32_bf16(av0, bv, acc0, 0, 0, 0);
                acc1 = __builtin_amdgcn_mfma_f32_16x16x32_bf16(av1, bv, acc1, 0, 0, 0);
            }
        }

        #pragma unroll
        for (int r = 0; r < 4; ++r) {
            red[wave][0][quad * 4 + r][l15] = acc0[r];
            red[wave][1][quad * 4 + r][l15] = acc1[r];
        }
        __syncthreads();

        int row = tid >> 4, col = tid & 15;
        #pragma unroll
        for (int nt = 0; nt < 2; ++nt) {
            float s = red[0][nt][row][col] + red[1][nt][row][col]
                    + red[2][nt][row][col] + red[3][nt][row][col];
            if (is_ai) {
                float ej = ejs[0][col] + ejs[1][col] + ejs[2][col] + ejs[3][col];
                float lg = tanhf(s + ej) * W_attn[jt * 16 + col];
                lg += __shfl_xor(lg, 1, 64);
                lg += __shfl_xor(lg, 2, 64);
                lg += __shfl_xor(lg, 4, 64);
                lg += __shfl_xor(lg, 8, 64);
                if (col == 0) lp[jt * 32 + nt * 16 + row] = lg;
            } else {
                fh_out[(size_t)(nt * 16 + row) * 2048 + jt * 16 + col] = s;
            }
        }
    } else {
        const float4* in4 = (const float4*)input;
        float4 xr[8];
        #pragma unroll
        for (int k = 0; k < 8; ++k) xr[k] = in4[lane + 64 * k];

        int r0 = (b - 256) * 16 + wave * 4;
        #pragma unroll
        for (int p = 0; p < 2; ++p) {
            int ra = r0 + p * 2;
            int rb = ra + 1;
            const float4* wa = (ra < 2048)
                ? (const float4*)(W_fi + (size_t)ra * 2048)
                : (const float4*)(W_iou + (size_t)(ra - 2048) * 4096);
            const float4* wb = (rb < 2048)
                ? (const float4*)(W_fi + (size_t)rb * 2048)
                : (const float4*)(W_iou + (size_t)(rb - 2048) * 4096);
            float4 A[8], B[8];
            #pragma unroll
            for (int k = 0; k < 8; ++k) { A[k] = wa[lane + 64 * k]; B[k] = wb[lane + 64 * k]; }
            float accA = 0.f, accB = 0.f;
            #pragma unroll
            for (int k = 0; k < 8; ++k) {
                accA += A[k].x*xr[k].x + A[k].y*xr[k].y + A[k].z*xr[k].z + A[k].w*xr[k].w;
                accB += B[k].x*xr[k].x + B[k].y*xr[k].y + B[k].z*xr[k].z + B[k].w*xr[k].w;
            }
            #pragma unroll
            for (int off = 32; off; off >>= 1) {
                accA += __shfl_down(accA, off, 64);
                accB += __shfl_down(accB, off, 64);
            }
            if (lane == 0) {
                if (ra < 2048) fi_out[ra] = accA; else iou_out[ra - 2048] = accA;
                if (rb < 2048) fi_out[rb] = accB; else iou_out[rb - 2048] = accB;
            }
        }
    }
}

// ===========================================================================
// K2. Grid 40 x 256:
//   blocks [0,32):  per-child LN stats of f_lin[n] = fi + fh[n] -> frs[n]
//                   (float4 loads + wave-shfl reduce, 1 barrier)
//   blocks [32,40): reduce lp partials -> softmax over 32 -> merged slice
// ===========================================================================
__global__ __launch_bounds__(256) void k2_mid(
    const float* __restrict__ fi, const float* __restrict__ fh,
    const float* __restrict__ lp, const float* __restrict__ hiddens,
    float* __restrict__ frs, float* __restrict__ merged)
{
    int b = blockIdx.x, t = threadIdx.x;
    int wave = t >> 6, lane = t & 63;

    if (b < 32) {
        __shared__ float pr[4][2];
        int n = b;
        const float4* fi4 = (const float4*)fi;
        const float4* fh4 = (const float4*)(fh + (size_t)n * 2048);
        float4 a0 = fi4[t * 2],     a1 = fi4[t * 2 + 1];
        float4 f0 = fh4[t * 2],     f1 = fh4[t * 2 + 1];
        float v0 = a0.x + f0.x, v1 = a0.y + f0.y, v2 = a0.z + f0.z, v3 = a0.w + f0.w;
        float v4 = a1.x + f1.x, v5 = a1.y + f1.y, v6 = a1.z + f1.z, v7 = a1.w + f1.w;
        float sum = v0 + v1 + v2 + v3 + v4 + v5 + v6 + v7;
        float sq  = v0*v0 + v1*v1 + v2*v2 + v3*v3 + v4*v4 + v5*v5 + v6*v6 + v7*v7;
        #pragma unroll
        for (int off = 1; off < 64; off <<= 1) {
            sum += __shfl_xor(sum, off, 64);
            sq  += __shfl_xor(sq,  off, 64);
        }
        if (lane == 0) { pr[wave][0] = sum; pr[wave][1] = sq; }
        __syncthreads();
        if (t == 0) {
            float s = pr[0][0] + pr[1][0] + pr[2][0] + pr[3][0];
            float q = pr[0][1] + pr[1][1] + pr[2][1] + pr[3][1];
            const float inv = 1.f / 2048.f;
            float mean = s * inv;
            frs[n * 2]     = mean;
            frs[n * 2 + 1] = rsqrtf(q * inv - mean * mean + EPSF);
        }
    } else {
        __shared__ float lred[32][8];
        __shared__ float attnw[32];
        int n = t >> 3, sl = t & 7;
        float p = 0.f;
        #pragma unroll
        for (int m = 0; m < 16; ++m) p += lp[(sl * 16 + m) * 32 + n];
        lred[n][sl] = p;
        __syncthreads();
        if (sl == 0) {
            float lg = 0.f;
            #pragma unroll
            for (int m = 0; m < 8; ++m) lg += lred[n][m];
            lred[n][0] = lg;
        }
        __syncthreads();
        if (t < 32) {
            float mx = -1e30f;
            for (int m = 0; m < 32; ++m) mx = fmaxf(mx, lred[m][0]);
            float ssum = 0.f;
            for (int m = 0; m < 32; ++m) ssum += expf(lred[m][0] - mx);
            attnw[t] = expf(lred[t][0] - mx) / ssum;
        }
        __syncthreads();
        int h = (b - 32) * 256 + t;
        float acc = 0.f;
        #pragma unroll 8
        for (int n2 = 0; n2 < 32; ++n2) acc += attnw[n2] * hiddens[n2 * 2048 + h];
        merged[h] = acc;
    }
}

// ===========================================================================
// K3. Grid 264 x 256:
//   blocks [0,256):   mm = W_merge @ merged, 8 rows/block, 2 rows/wave,
//                     pairwise batched loads.
//   blocks [256,264): fc[h] = sum_n sigmoid(LN_n(fi+fh)[h]*g+b)*cells[n][h]
// ===========================================================================
__global__ __launch_bounds__(256) void k3_mid(
    const float* __restrict__ W_merge, const float* __restrict__ merged,
    const float* __restrict__ fi, const float* __restrict__ fh,
    const float* __restrict__ frs, const float* __restrict__ gf,
    const float* __restrict__ bf_, const float* __restrict__ cells,
    float* __restrict__ mm, float* __restrict__ fc)
{
    int b = blockIdx.x, t = threadIdx.x;
    int wave = t >> 6, lane = t & 63;
    if (b < 256) {
        const float4* xp = (const float4*)merged;
        float4 xr[8];
        #pragma unroll
        for (int k = 0; k < 8; ++k) xr[k] = xp[lane + 64 * k];

        int ra = b * 8 + wave * 2;
        int rb = ra + 1;
        const float4* wa = (const float4*)(W_merge + (size_t)ra * 2048);
        const float4* wb = (const float4*)(W_merge + (size_t)rb * 2048);
        float4 A[8], B[8];
        #pragma unroll
        for (int k = 0; k < 8; ++k) { A[k] = wa[lane + 64 * k]; B[k] = wb[lane + 64 * k]; }
        float accA = 0.f, accB = 0.f;
        #pragma unroll
        for (int k = 0; k < 8; ++k) {
            accA += A[k].x*xr[k].x + A[k].y*xr[k].y + A[k].z*xr[k].z + A[k].w*xr[k].w;
            accB += B[k].x*xr[k].x + B[k].y*xr[k].y + B[k].z*xr[k].z + B[k].w*xr[k].w;
        }
        #pragma unroll
        for (int off = 32; off; off >>= 1) {
            accA += __shfl_down(accA, off, 64);
            accB += __shfl_down(accB, off, 64);
        }
        if (lane == 0) { mm[ra] = accA; mm[rb] = accB; }
    } else {
        int h = (b - 256) * 256 + t;
        float g = gf[h], bb = bf_[h], f_i = fi[h];
        float acc = 0.f;
        #pragma unroll 8
        for (int n = 0; n < 32; ++n) {
            float v = (f_i + fh[n * 2048 + h] - frs[n * 2]) * frs[n * 2 + 1] * g + bb;
            float f = 1.f / (1.f + expf(-v));
            acc += f * cells[n * 2048 + h];
        }
        fc[h] = acc;
    }
}

// ===========================================================================
// K4. Grid 768 x 256 (3 blocks/CU): iou mh-half.  [r5 champion config]
// Block prologue: mh = tanh(LN(mm)*g+b) once into LDS (shfl + LDS combine).
// Then 2 rows/wave of W_iou[:, 2048:], all 16 row-loads batched before any
// reduce; iou[row] += dot (input-half partial from K1). No fence/atomic.
// ===========================================================================
__global__ __launch_bounds__(256, 3) void k4_mh(
    const float* __restrict__ W_iou, const float* __restrict__ mm,
    const float* __restrict__ g_merge, const float* __restrict__ b_merge,
    float* __restrict__ iou)
{
    __shared__ float mh_lds[2048];
    __shared__ float pr[4][2];
    int b = blockIdx.x, t = threadIdx.x;
    int wave = t >> 6, lane = t & 63;

    const float4* mm4 = (const float4*)mm;
    const float4* g4  = (const float4*)g_merge;
    const float4* b4  = (const float4*)b_merge;

    float4 m0 = mm4[t * 2], m1 = mm4[t * 2 + 1];
    float sum = m0.x + m0.y + m0.z + m0.w + m1.x + m1.y + m1.z + m1.w;
    float sq  = m0.x*m0.x + m0.y*m0.y + m0.z*m0.z + m0.w*m0.w
              + m1.x*m1.x + m1.y*m1.y + m1.z*m1.z + m1.w*m1.w;
    #pragma unroll
    for (int off = 1; off < 64; off <<= 1) {
        sum += __shfl_xor(sum, off, 64);
        sq  += __shfl_xor(sq,  off, 64);
    }
    if (lane == 0) { pr[wave][0] = sum; pr[wave][1] = sq; }
    __syncthreads();
    sum = pr[0][0] + pr[1][0] + pr[2][0] + pr[3][0];
    sq  = pr[0][1] + pr[1][1] + pr[2][1] + pr[3][1];
    const float inv = 1.f / 2048.f;
    float mean = sum * inv;
    float r = rsqrtf(sq * inv - mean * mean + EPSF);

    float4 g0 = g4[t * 2], g1 = g4[t * 2 + 1];
    float4 c0 = b4[t * 2], c1 = b4[t * 2 + 1];
    float4 h0, h1;
    h0.x = tanhf((m0.x - mean) * r * g0.x + c0.x);
    h0.y = tanhf((m0.y - mean) * r * g0.y + c0.y);
    h0.z = tanhf((m0.z - mean) * r * g0.z + c0.z);
    h0.w = tanhf((m0.w - mean) * r * g0.w + c0.w);
    h1.x = tanhf((m1.x - mean) * r * g1.x + c1.x);
    h1.y = tanhf((m1.y - mean) * r * g1.y + c1.y);
    h1.z = tanhf((m1.z - mean) * r * g1.z + c1.z);
    h1.w = tanhf((m1.w - mean) * r * g1.w + c1.w);
    ((float4*)mh_lds)[t * 2]     = h0;
    ((float4*)mh_lds)[t * 2 + 1] = h1;
    __syncthreads();

    float4 xr[8];
    #pragma unroll
    for (int k = 0; k < 8; ++k) xr[k] = ((const float4*)mh_lds)[lane + 64 * k];

    int ra = b * 8 + wave * 2;
    int rb = ra + 1;
    const float4* wa = (const float4*)(W_iou + (size_t)ra * 4096 + 2048);
    const float4* wb = (const float4*)(W_iou + (size_t)rb * 4096 + 2048);
    float4 A[8], B[8];
    #pragma unroll
    for (int k = 0; k < 8; ++k) { A[k] = wa[lane + 64 * k]; B[k] = wb[lane + 64 * k]; }
    float accA = 0.f, accB = 0.f;
    #pragma unroll
    for (int k = 0; k < 8; ++k) {
        accA += A[k].x*xr[k].x + A[k].y*xr[k].y + A[k].z*xr[k].z + A[k].w*xr[k].w;
        accB += B[k].x*xr[k].x + B[k].y*xr[k].y + B[k].z*xr[k].z + B[k].w*xr[k].w;
    }
    #pragma unroll
    for (int off = 32; off; off >>= 1) {
        accA += __shfl_down(accA, off, 64);
        accB += __shfl_down(accB, off, 64);
    }
    if (lane == 0) { iou[ra] += accA; iou[rb] += accB; }
}

// ===========================================================================
// K5: fused tail — i/o/u LN stats + gates, v = i*u + fc, LN(v), fp32 out.
// One block of 256.
// ===========================================================================
__global__ __launch_bounds__(256) void k5_tail(
    const float* __restrict__ iou, const float* __restrict__ fc,
    const float* __restrict__ gi, const float* __restrict__ bi,
    const float* __restrict__ go, const float* __restrict__ bo,
    const float* __restrict__ gu, const float* __restrict__ bu,
    const float* __restrict__ gc, const float* __restrict__ bc,
    float* __restrict__ out)
{
    __shared__ float sA[6][256];
    int t = threadIdx.x;
    float vi[8], vo[8], vu[8];
    float si = 0, qi = 0, so = 0, qo = 0, su = 0, qu = 0;
    #pragma unroll
    for (int i = 0; i < 8; ++i) {
        int h = t * 8 + i;
        vi[i] = iou[h]; vo[i] = iou[2048 + h]; vu[i] = iou[4096 + h];
        si += vi[i]; qi += vi[i] * vi[i];
        so += vo[i]; qo += vo[i] * vo[i];
        su += vu[i]; qu += vu[i] * vu[i];
    }
    sA[0][t] = si; sA[1][t] = qi; sA[2][t] = so;
    sA[3][t] = qo; sA[4][t] = su; sA[5][t] = qu;
    __syncthreads();
    for (int off = 128; off; off >>= 1) {
        if (t < off) {
            #pragma unroll
            for (int c = 0; c < 6; ++c) sA[c][t] += sA[c][t + off];
        }
        __syncthreads();
    }
    const float inv = 1.f / 2048.f;
    float mi = sA[0][0] * inv, ri = rsqrtf(sA[1][0] * inv - mi * mi + EPSF);
    float mo = sA[2][0] * inv, ro = rsqrtf(sA[3][0] * inv - mo * mo + EPSF);
    float mu = sA[4][0] * inv, ru = rsqrtf(sA[5][0] * inv - mu * mu + EPSF);
    __syncthreads();

    float o_[8], v_[8];
    float sv = 0, qv = 0;
    #pragma unroll
    for (int i = 0; i < 8; ++i) {
        int h = t * 8 + i;
        float ivl = 1.f / (1.f + expf(-((vi[i] - mi) * ri * gi[h] + bi[h])));
        o_[i]     = 1.f / (1.f + expf(-((vo[i] - mo) * ro * go[h] + bo[h])));
        float uvl = tanhf((vu[i] - mu) * ru * gu[h] + bu[h]);
        v_[i] = ivl * uvl + fc[h];
        sv += v_[i]; qv += v_[i] * v_[i];
    }
    sA[0][t] = sv; sA[1][t] = qv;
    __syncthreads();
    for (int off = 128; off; off >>= 1) {
        if (t < off) { sA[0][t] += sA[0][t + off]; sA[1][t] += sA[1][t + off]; }
        __syncthreads();
    }
    float mc = sA[0][0] * inv, rc = rsqrtf(sA[1][0] * inv - mc * mc + EPSF);
    #pragma unroll
    for (int i = 0; i < 8; ++i) {
        int h = t * 8 + i;
        float nc = (v_[i] - mc) * rc * gc[h] + bc[h];
        float nh = o_[i] * tanhf(nc);
        out[h]        = nh;
        out[2048 + h] = nc;
    }
}

// ---------------------------------------------------------------------------
extern "C" void kernel_launch(void* const* d_in, const int* in_sizes, int n_in,
                              void* d_out, int out_size, void* d_ws, size_t ws_size,
                              hipStream_t stream)
{
    const float* input    = (const float*)d_in[0];
    const float* hiddens  = (const float*)d_in[1];
    const float* cells    = (const float*)d_in[2];
    const float* external = (const float*)d_in[3];
    const float* W_ai     = (const float*)d_in[4];
    const float* W_attn   = (const float*)d_in[5];
    const float* W_merge  = (const float*)d_in[6];
    const float* W_iou    = (const float*)d_in[7];
    const float* W_fi     = (const float*)d_in[8];
    const float* W_fh     = (const float*)d_in[9];
    const float* g_merge  = (const float*)d_in[10];
    const float* b_merge  = (const float*)d_in[11];
    const float* g_f      = (const float*)d_in[12];
    const float* b_f      = (const float*)d_in[13];
    const float* g_i      = (const float*)d_in[14];
    const float* b_i      = (const float*)d_in[15];
    const float* g_o      = (const float*)d_in[16];
    const float* b_o      = (const float*)d_in[17];
    const float* g_u      = (const float*)d_in[18];
    const float* b_u      = (const float*)d_in[19];
    const float* g_c      = (const float*)d_in[20];
    const float* b_c      = (const float*)d_in[21];

    float* ws = (float*)d_ws;
    float* ws_fh     = ws;              // 32*2048 = 65536
    float* ws_fi     = ws + 65536;      // 2048
    float* ws_lp     = ws + 67584;      // 128*32 = 4096
    float* ws_frs    = ws + 71680;      // 64
    float* ws_merged = ws + 71744;      // 2048
    float* ws_mm     = ws + 73792;      // 2048
    float* ws_fc     = ws + 75840;      // 2048
    float* ws_iou    = ws + 77888;      // 6144
    float* out = (float*)d_out;

    k1_streams<<<768, 256, 0, stream>>>(hiddens, external, input,
                                        W_ai, W_fh, W_fi, W_iou, W_attn,
                                        ws_lp, ws_fh, ws_fi, ws_iou);
    k2_mid<<<40, 256, 0, stream>>>(ws_fi, ws_fh, ws_lp, hiddens,
                                   ws_frs, ws_merged);
    k3_mid<<<264, 256, 0, stream>>>(W_merge, ws_merged, ws_fi, ws_fh,
                                    ws_frs, g_f, b_f, cells, ws_mm, ws_fc);
    k4_mh<<<768, 256, 0, stream>>>(W_iou, ws_mm, g_merge, b_merge, ws_iou);
    k5_tail<<<1, 256, 0, stream>>>(ws_iou, ws_fc, g_i, b_i, g_o, b_o,
                                   g_u, b_u, g_c, b_c, out);
}